// Round 4
// baseline (1204.171 us; speedup 1.0000x reference)
//
#include <hip/hip_runtime.h>
#include <hip/hip_bf16.h>
#include <math.h>

#define D 512
#define BB 4
#define TT 4096
#define KT 32

typedef __attribute__((ext_vector_type(8))) short short8v;
typedef __attribute__((ext_vector_type(4))) short short4v;
typedef __attribute__((ext_vector_type(4))) float float4v;

__device__ inline short f2bf(float x) {
    __hip_bfloat16 h = __float2bfloat16(x);
    return *reinterpret_cast<short*>(&h);
}

// ============ QKV projection: C[t][e] = alpha * sum_d x[t][d] * W[e][d], bf16 out ============
__global__ __launch_bounds__(256) void gemm_qkv(
    const float* __restrict__ x,
    const float* __restrict__ Wq, const float* __restrict__ Wk, const float* __restrict__ Wv,
    __hip_bfloat16* __restrict__ q, __hip_bfloat16* __restrict__ k, __hip_bfloat16* __restrict__ v)
{
    const float* W; __hip_bfloat16* C; float alpha;
    if (blockIdx.z == 0)      { W = Wq; C = q; alpha = 0.044194173824159216f; } // fold 1/sqrt(512)
    else if (blockIdx.z == 1) { W = Wk; C = k; alpha = 1.f; }
    else                      { W = Wv; C = v; alpha = 1.f; }

    __shared__ short As[64][72];   // +8 bf16 pad -> conflict-floor b128 reads
    __shared__ short Bs[64][72];
    const int tid = threadIdx.x;
    const int m0 = blockIdx.x * 64, n0 = blockIdx.y * 64;
    const int w = tid >> 6, lane = tid & 63, lm = lane & 15, g = lane >> 4;

    float4v acc[4];
    #pragma unroll
    for (int i = 0; i < 4; ++i) acc[i] = (float4v){0.f,0.f,0.f,0.f};

    for (int k0 = 0; k0 < 512; k0 += 64) {
        __syncthreads();
        #pragma unroll
        for (int u = 0; u < 4; ++u) {          // stage A (x), convert f32->bf16
            int ch = tid + 256*u;
            int r = ch >> 4, c = (ch & 15) * 4;
            float4 xv = *reinterpret_cast<const float4*>(x + (size_t)(m0 + r)*512 + k0 + c);
            short4v sv = { f2bf(xv.x), f2bf(xv.y), f2bf(xv.z), f2bf(xv.w) };
            *reinterpret_cast<short4v*>(&As[r][c]) = sv;
        }
        #pragma unroll
        for (int u = 0; u < 4; ++u) {          // stage B (W rows)
            int ch = tid + 256*u;
            int r = ch >> 4, c = (ch & 15) * 4;
            float4 wv = *reinterpret_cast<const float4*>(W + (size_t)(n0 + r)*512 + k0 + c);
            short4v sv = { f2bf(wv.x), f2bf(wv.y), f2bf(wv.z), f2bf(wv.w) };
            *reinterpret_cast<short4v*>(&Bs[r][c]) = sv;
        }
        __syncthreads();
        #pragma unroll
        for (int ks = 0; ks < 2; ++ks) {
            short8v a = *reinterpret_cast<const short8v*>(&As[16*w + lm][ks*32 + 8*g]);
            #pragma unroll
            for (int nt = 0; nt < 4; ++nt) {
                short8v bv = *reinterpret_cast<const short8v*>(&Bs[16*nt + lm][ks*32 + 8*g]);
                acc[nt] = __builtin_amdgcn_mfma_f32_16x16x32_bf16(a, bv, acc[nt], 0, 0, 0);
            }
        }
    }
    #pragma unroll
    for (int nt = 0; nt < 4; ++nt)
        #pragma unroll
        for (int r = 0; r < 4; ++r) {
            int row = m0 + 16*w + 4*g + r;     // D: row = 4*(lane>>4)+reg, col = lane&15
            int col = n0 + 16*nt + lm;
            C[(size_t)row*512 + col] = __float2bfloat16(acc[nt][r] * alpha);
        }
}

// ============ V transpose with sigma-permuted columns ============
// vt[b][d][32-block of t, order pos(tau)] so a PV B-fragment is ONE contiguous 16B load.
// pos(tau) = 8*((tau&15)>>2) + (tau&3) + 4*(tau>>4): lane g reads pos 8g..8g+7 =
// keys {4g..4g+3, 16+4g..16+4g+3} — exactly the MFMA sigma the P-fragment carries.
__global__ __launch_bounds__(256) void transpose_v(
    const __hip_bfloat16* __restrict__ vin, __hip_bfloat16* __restrict__ vout)
{
    const int tid = threadIdx.x;
    const int b = blockIdx.y;
    const int t = blockIdx.x * 32 + (tid & 31);
    const int tau = t & 31;
    const int tp = (t & ~31) + 8*((tau & 15) >> 2) + (tau & 3) + 4*(tau >> 4);
    const short* src = (const short*)vin + (size_t)(b*TT + t)*D;
    short* dst = (short*)vout + (size_t)b*D*TT;
    #pragma unroll
    for (int u = 0; u < 8; ++u) {
        int cf = (tid >> 5) + 8*u;             // 0..63 (16B chunk within row)
        short8v vv = *reinterpret_cast<const short8v*>(src + cf*8);
        #pragma unroll
        for (int i = 0; i < 8; ++i)
            dst[(size_t)(cf*8 + i)*TT + tp] = vv[i];
    }
}

// ============ Flash attention: 2 waves/block, K shared in double-buffered LDS ============
// K staged via global_load_lds into LINEAR LDS with XOR-pre-swizzled SOURCE (rule #21):
// LDS[r][chunk j] holds K[r][chunk j ^ (r&7)]; reads XOR the same way -> 2-way floor.
// V read direct from sigma-permuted global vt (replay-proven R3 path). One barrier/tile;
// double buffer means stage(t+1) writes touch a buffer whose last reads finished a full
// barrier earlier.
__global__ __launch_bounds__(128, 2) void attn(
    const __hip_bfloat16* __restrict__ qg, const __hip_bfloat16* __restrict__ kg,
    const __hip_bfloat16* __restrict__ vtg, __hip_bfloat16* __restrict__ ctx)
{
    __shared__ short Ks[2][KT][512];           // 64KB, linear (global_load_lds target)

    const int tid = threadIdx.x;
    const int w = tid >> 6, lane = tid & 63, lm = lane & 15, g = lane >> 4;
    const int idx = blockIdx.x;
    const int b  = idx & 3;                    // batch -> XCD spread
    const int qb = 127 - (idx >> 2);           // descending work order
    const int qbase = qb * 32;
    const int qrow  = qbase + 16*w + lm;

    const short* qp = (const short*)qg  + (size_t)b*TT*D;
    const short* kp = (const short*)kg  + (size_t)b*TT*D;
    const short* vp = (const short*)vtg + (size_t)b*D*TT;

    // hoist Q fragments: lane (g,lm) holds Q[qrow][32s+8g .. +8]
    short8v qf[16];
    #pragma unroll
    for (int s = 0; s < 16; ++s)
        qf[s] = *reinterpret_cast<const short8v*>(qp + (size_t)qrow*D + 32*s + 8*g);

    float4v acc[32];
    #pragma unroll
    for (int i = 0; i < 32; ++i) acc[i] = (float4v){0.f,0.f,0.f,0.f};
    float m_r = -INFINITY, l_r = 0.f;

    const int ntiles = qb + 1;

    // stage tile t into buffer buf: wave w DMAs rows 16w..16w+15 (1 row = 1 instr = 1KB)
    #define STAGE_K(T, BUF) do {                                                   \
        const short* kt_ = kp + (size_t)(T) * KT * D;                              \
        _Pragma("unroll")                                                          \
        for (int i_ = 0; i_ < 16; ++i_) {                                          \
            int r_ = 16*w + i_;                                                    \
            int c_ = ((lane & 56) | ((lane ^ r_) & 7)) << 3;  /* src chunk swz */  \
            __builtin_amdgcn_global_load_lds(                                      \
                (const __attribute__((address_space(1))) void*)(kt_ + (size_t)r_*D + c_), \
                (__attribute__((address_space(3))) void*)(&Ks[BUF][r_][0]),        \
                16, 0, 0);                                                         \
        }                                                                          \
    } while (0)

    STAGE_K(0, 0);

    for (int t = 0; t < ntiles; ++t) {
        const int ks0 = t * KT;
        const int cur = t & 1;
        __syncthreads();                       // drains own vmcnt/lgkmcnt, then barrier:
                                               // all waves' stage(t) writes landed,
                                               // all waves' compute(t-1) reads done
        if (t + 1 < ntiles) STAGE_K(t + 1, cur ^ 1);

        // S^T[kj][q]: 2 subtiles of 16 kj; A-frag from swizzled LDS
        float4v s0 = (float4v){0.f,0.f,0.f,0.f}, s1 = (float4v){0.f,0.f,0.f,0.f};
        #pragma unroll
        for (int s = 0; s < 16; ++s) {
            int j = (4*s + g) ^ (lm & 7);      // chunk swizzle: row&7 == lm&7 for both subs
            short8v a0 = *reinterpret_cast<const short8v*>(&Ks[cur][lm][j*8]);
            short8v a1 = *reinterpret_cast<const short8v*>(&Ks[cur][16 + lm][j*8]);
            s0 = __builtin_amdgcn_mfma_f32_16x16x32_bf16(a0, qf[s], s0, 0, 0, 0);
            s1 = __builtin_amdgcn_mfma_f32_16x16x32_bf16(a1, qf[s], s1, 0, 0, 0);
        }

        // causal mask + online softmax; lane holds kj = ks0 + 16*sub + 4g + r for q = qrow
        float p[8];
        #pragma unroll
        for (int r = 0; r < 4; ++r) {
            int kj0 = ks0 + 4*g + r;
            p[r]     = (kj0      <= qrow) ? s0[r] : -3.0e38f;
            p[r + 4] = (kj0 + 16 <= qrow) ? s1[r] : -3.0e38f;
        }
        float mx = p[0];
        #pragma unroll
        for (int i = 1; i < 8; ++i) mx = fmaxf(mx, p[i]);
        mx = fmaxf(mx, __shfl_xor(mx, 16));
        mx = fmaxf(mx, __shfl_xor(mx, 32));
        float mnew = fmaxf(m_r, mx);
        float corr = __expf(m_r - mnew);       // first tile: expf(-inf)=0
        float psum = 0.f;
        #pragma unroll
        for (int i = 0; i < 8; ++i) { p[i] = __expf(p[i] - mnew); psum += p[i]; }
        psum += __shfl_xor(psum, 16);
        psum += __shfl_xor(psum, 32);
        l_r = l_r * corr + psum;
        m_r = mnew;

        float c4[4];
        #pragma unroll
        for (int r = 0; r < 4; ++r) c4[r] = __shfl(corr, 4*g + r);  // corr for acc-row q=16w+4g+r
        #pragma unroll
        for (int dt = 0; dt < 32; ++dt) {
            acc[dt][0] *= c4[0]; acc[dt][1] *= c4[1];
            acc[dt][2] *= c4[2]; acc[dt][3] *= c4[3];
        }

        // P fragment (lane-local, matches V sigma)
        short8v pf;
        #pragma unroll
        for (int i = 0; i < 8; ++i) pf[i] = f2bf(p[i]);

        // PV: B-frag = one contiguous 16B load from sigma-permuted vt (global, L1-shared)
        #pragma unroll
        for (int dt = 0; dt < 32; ++dt) {
            const short* vrow = vp + (size_t)(16*dt + lm)*TT + ks0 + 8*g;
            short8v v0 = *reinterpret_cast<const short8v*>(vrow);
            acc[dt] = __builtin_amdgcn_mfma_f32_16x16x32_bf16(pf, v0, acc[dt], 0, 0, 0);
        }
    }
    #undef STAGE_K

    float inv = 1.f / l_r;
    float i4[4];
    #pragma unroll
    for (int r = 0; r < 4; ++r) i4[r] = __shfl(inv, 4*g + r);
    __hip_bfloat16* cp = ctx + (size_t)b*TT*D;
    #pragma unroll
    for (int dt = 0; dt < 32; ++dt)
        #pragma unroll
        for (int r = 0; r < 4; ++r) {
            int row = qbase + 16*w + 4*g + r;
            cp[(size_t)row*D + 16*dt + lm] = __float2bfloat16(acc[dt][r] * i4[r]);
        }
}

// ============ Output projection: d_out[t][e] = sum_d ctx[t][d] * Wo[e][d], f32 out ============
__global__ __launch_bounds__(256) void gemm_out(
    const __hip_bfloat16* __restrict__ Ab, const float* __restrict__ W,
    float* __restrict__ Cf)
{
    __shared__ short As[64][72];
    __shared__ short Bs[64][72];
    const int tid = threadIdx.x;
    const int m0 = blockIdx.x * 64, n0 = blockIdx.y * 64;
    const int w = tid >> 6, lane = tid & 63, lm = lane & 15, g = lane >> 4;
    const short* Ap = (const short*)Ab;

    float4v acc[4];
    #pragma unroll
    for (int i = 0; i < 4; ++i) acc[i] = (float4v){0.f,0.f,0.f,0.f};

    for (int k0 = 0; k0 < 512; k0 += 64) {
        __syncthreads();
        #pragma unroll
        for (int u = 0; u < 2; ++u) {          // stage A (bf16 ctx)
            int ch = tid + 256*u;
            int r = ch >> 3, c = (ch & 7) * 8;
            *reinterpret_cast<short8v*>(&As[r][c]) =
                *reinterpret_cast<const short8v*>(Ap + (size_t)(m0 + r)*512 + k0 + c);
        }
        #pragma unroll
        for (int u = 0; u < 4; ++u) {          // stage B (Wo f32 -> bf16)
            int ch = tid + 256*u;
            int r = ch >> 4, c = (ch & 15) * 4;
            float4 wv = *reinterpret_cast<const float4*>(W + (size_t)(n0 + r)*512 + k0 + c);
            short4v sv = { f2bf(wv.x), f2bf(wv.y), f2bf(wv.z), f2bf(wv.w) };
            *reinterpret_cast<short4v*>(&Bs[r][c]) = sv;
        }
        __syncthreads();
        #pragma unroll
        for (int ks = 0; ks < 2; ++ks) {
            short8v a = *reinterpret_cast<const short8v*>(&As[16*w + lm][ks*32 + 8*g]);
            #pragma unroll
            for (int nt = 0; nt < 4; ++nt) {
                short8v bv = *reinterpret_cast<const short8v*>(&Bs[16*nt + lm][ks*32 + 8*g]);
                acc[nt] = __builtin_amdgcn_mfma_f32_16x16x32_bf16(a, bv, acc[nt], 0, 0, 0);
            }
        }
    }
    #pragma unroll
    for (int nt = 0; nt < 4; ++nt)
        #pragma unroll
        for (int r = 0; r < 4; ++r) {
            int row = m0 + 16*w + 4*g + r;
            int col = n0 + 16*nt + lm;
            Cf[(size_t)row*512 + col] = acc[nt][r];
        }
}

extern "C" void kernel_launch(void* const* d_in, const int* in_sizes, int n_in,
                              void* d_out, int out_size, void* d_ws, size_t ws_size,
                              hipStream_t stream) {
    const float* x  = (const float*)d_in[0];
    const float* Wq = (const float*)d_in[1];
    const float* Wk = (const float*)d_in[2];
    const float* Wv = (const float*)d_in[3];
    const float* Wo = (const float*)d_in[4];
    float* out = (float*)d_out;

    const size_t n = (size_t)BB * TT * D;                 // 8.4M elems
    __hip_bfloat16* qb   = (__hip_bfloat16*)d_ws;
    __hip_bfloat16* kb   = qb + n;
    __hip_bfloat16* vb   = kb + n;
    __hip_bfloat16* vt   = vb + n;
    __hip_bfloat16* ctxb = vt + n;                        // total 5n*2B = 80MB

    gemm_qkv<<<dim3(256, 8, 3), 256, 0, stream>>>(x, Wq, Wk, Wv, qb, kb, vb);
    transpose_v<<<dim3(TT / 32, BB), 256, 0, stream>>>(vb, vt);
    attn<<<dim3(128 * BB), 128, 0, stream>>>(qb, kb, vt, ctxb);
    gemm_out<<<dim3(256, 8, 1), 256, 0, stream>>>(ctxb, Wo, out);
}

// Round 5
// 530.865 us; speedup vs baseline: 2.2683x; 2.2683x over previous
//
#include <hip/hip_runtime.h>
#include <hip/hip_bf16.h>
#include <math.h>

#define D 512
#define BB 4
#define TT 4096
#define KT 32

typedef __attribute__((ext_vector_type(8))) short short8v;
typedef __attribute__((ext_vector_type(4))) short short4v;
typedef __attribute__((ext_vector_type(4))) float float4v;

__device__ inline short f2bf(float x) {
    __hip_bfloat16 h = __float2bfloat16(x);
    return *reinterpret_cast<short*>(&h);
}

// ============ QKV projection: C[t][e] = alpha * sum_d x[t][d] * W[e][d], bf16 out ============
__global__ __launch_bounds__(256) void gemm_qkv(
    const float* __restrict__ x,
    const float* __restrict__ Wq, const float* __restrict__ Wk, const float* __restrict__ Wv,
    __hip_bfloat16* __restrict__ q, __hip_bfloat16* __restrict__ k, __hip_bfloat16* __restrict__ v)
{
    const float* W; __hip_bfloat16* C; float alpha;
    if (blockIdx.z == 0)      { W = Wq; C = q; alpha = 0.044194173824159216f; } // fold 1/sqrt(512)
    else if (blockIdx.z == 1) { W = Wk; C = k; alpha = 1.f; }
    else                      { W = Wv; C = v; alpha = 1.f; }

    __shared__ short As[64][72];   // +8 bf16 pad -> conflict-floor b128 reads
    __shared__ short Bs[64][72];
    const int tid = threadIdx.x;
    const int m0 = blockIdx.x * 64, n0 = blockIdx.y * 64;
    const int w = tid >> 6, lane = tid & 63, lm = lane & 15, g = lane >> 4;

    float4v acc[4];
    #pragma unroll
    for (int i = 0; i < 4; ++i) acc[i] = (float4v){0.f,0.f,0.f,0.f};

    for (int k0 = 0; k0 < 512; k0 += 64) {
        __syncthreads();
        #pragma unroll
        for (int u = 0; u < 4; ++u) {          // stage A (x), convert f32->bf16
            int ch = tid + 256*u;
            int r = ch >> 4, c = (ch & 15) * 4;
            float4 xv = *reinterpret_cast<const float4*>(x + (size_t)(m0 + r)*512 + k0 + c);
            short4v sv = { f2bf(xv.x), f2bf(xv.y), f2bf(xv.z), f2bf(xv.w) };
            *reinterpret_cast<short4v*>(&As[r][c]) = sv;
        }
        #pragma unroll
        for (int u = 0; u < 4; ++u) {          // stage B (W rows)
            int ch = tid + 256*u;
            int r = ch >> 4, c = (ch & 15) * 4;
            float4 wv = *reinterpret_cast<const float4*>(W + (size_t)(n0 + r)*512 + k0 + c);
            short4v sv = { f2bf(wv.x), f2bf(wv.y), f2bf(wv.z), f2bf(wv.w) };
            *reinterpret_cast<short4v*>(&Bs[r][c]) = sv;
        }
        __syncthreads();
        #pragma unroll
        for (int ks = 0; ks < 2; ++ks) {
            short8v a = *reinterpret_cast<const short8v*>(&As[16*w + lm][ks*32 + 8*g]);
            #pragma unroll
            for (int nt = 0; nt < 4; ++nt) {
                short8v bv = *reinterpret_cast<const short8v*>(&Bs[16*nt + lm][ks*32 + 8*g]);
                acc[nt] = __builtin_amdgcn_mfma_f32_16x16x32_bf16(a, bv, acc[nt], 0, 0, 0);
            }
        }
    }
    #pragma unroll
    for (int nt = 0; nt < 4; ++nt)
        #pragma unroll
        for (int r = 0; r < 4; ++r) {
            int row = m0 + 16*w + 4*g + r;     // D: row = 4*(lane>>4)+reg, col = lane&15
            int col = n0 + 16*nt + lm;
            C[(size_t)row*512 + col] = __float2bfloat16(acc[nt][r] * alpha);
        }
}

// ============ V transpose with sigma-permuted columns ============
// vt[b][d][32-block of t, order pos(tau)] so a PV B-fragment is ONE contiguous 16B load.
__global__ __launch_bounds__(256) void transpose_v(
    const __hip_bfloat16* __restrict__ vin, __hip_bfloat16* __restrict__ vout)
{
    const int tid = threadIdx.x;
    const int b = blockIdx.y;
    const int t = blockIdx.x * 32 + (tid & 31);
    const int tau = t & 31;
    const int tp = (t & ~31) + 8*((tau & 15) >> 2) + (tau & 3) + 4*(tau >> 4);
    const short* src = (const short*)vin + (size_t)(b*TT + t)*D;
    short* dst = (short*)vout + (size_t)b*D*TT;
    #pragma unroll
    for (int u = 0; u < 8; ++u) {
        int cf = (tid >> 5) + 8*u;             // 0..63 (16B chunk within row)
        short8v vv = *reinterpret_cast<const short8v*>(src + cf*8);
        #pragma unroll
        for (int i = 0; i < 8; ++i)
            dst[(size_t)(cf*8 + i)*TT + tp] = vv[i];
    }
}

// ============ Flash attention: 4 waves/block = 2 q-groups x 2 d-halves ============
// Wave (qgp,dh): 16 q-rows (qbase+16*qgp..), output dims [dh*256, dh*256+256).
// QK^T + softmax computed redundantly per d-half (zero cross-wave comms; MFMA pipe idle
// anyway); PV and V loads split by d-half -> acc halves to 64 VGPRs. K tile (32x512,
// double-buffered 64KB) shared by all 4 waves via global_load_lds with source-XOR swizzle.
// 512 blocks x 4 waves = 2 blocks/CU, 2 waves/SIMD.
__global__ __launch_bounds__(256, 2) void attn(
    const __hip_bfloat16* __restrict__ qg, const __hip_bfloat16* __restrict__ kg,
    const __hip_bfloat16* __restrict__ vtg, __hip_bfloat16* __restrict__ ctx)
{
    __shared__ short Ks[2][KT][512];           // 64KB, linear (global_load_lds target)

    const int tid = threadIdx.x;
    const int w = tid >> 6, lane = tid & 63, lm = lane & 15, g = lane >> 4;
    const int qgp = w & 1, dh = w >> 1;
    const int idx = blockIdx.x;
    const int b  = idx & 3;                    // batch -> XCD spread
    const int qb = 127 - (idx >> 2);           // descending work order
    const int qbase = qb * 32;
    const int qrow  = qbase + 16*qgp + lm;

    const short* qp = (const short*)qg  + (size_t)b*TT*D;
    const short* kp = (const short*)kg  + (size_t)b*TT*D;
    const short* vp = (const short*)vtg + (size_t)b*D*TT;

    // hoist Q fragments: lane (g,lm) holds Q[qrow][32s+8g .. +8]
    short8v qf[16];
    #pragma unroll
    for (int s = 0; s < 16; ++s)
        qf[s] = *reinterpret_cast<const short8v*>(qp + (size_t)qrow*D + 32*s + 8*g);

    float4v acc[16];                           // dims dh*256 + 16*dtl + lm
    #pragma unroll
    for (int i = 0; i < 16; ++i) acc[i] = (float4v){0.f,0.f,0.f,0.f};
    float m_r = -INFINITY, l_r = 0.f;

    const int ntiles = qb + 1;

    // stage tile T into buffer BUF: wave w DMAs rows 8w..8w+7 (1 row = 1 instr = 1KB)
    #define STAGE_K(T, BUF) do {                                                   \
        const short* kt_ = kp + (size_t)(T) * KT * D;                              \
        _Pragma("unroll")                                                          \
        for (int i_ = 0; i_ < 8; ++i_) {                                           \
            int r_ = 8*w + i_;                                                     \
            int c_ = ((lane & 56) | ((lane ^ r_) & 7)) << 3;  /* src chunk swz */  \
            __builtin_amdgcn_global_load_lds(                                      \
                (const __attribute__((address_space(1))) void*)(kt_ + (size_t)r_*D + c_), \
                (__attribute__((address_space(3))) void*)(&Ks[BUF][r_][0]),        \
                16, 0, 0);                                                         \
        }                                                                          \
    } while (0)

    STAGE_K(0, 0);

    for (int t = 0; t < ntiles; ++t) {
        const int ks0 = t * KT;
        const int cur = t & 1;
        __syncthreads();                       // own vmcnt drained -> stage(t) landed for all
        if (t + 1 < ntiles) STAGE_K(t + 1, cur ^ 1);

        // S^T[kj][q]: 2 subtiles of 16 kj; A-frag from swizzled LDS
        float4v s0 = (float4v){0.f,0.f,0.f,0.f}, s1 = (float4v){0.f,0.f,0.f,0.f};
        #pragma unroll
        for (int s = 0; s < 16; ++s) {
            int j = (4*s + g) ^ (lm & 7);      // chunk swizzle: row&7 == lm&7 for both subs
            short8v a0 = *reinterpret_cast<const short8v*>(&Ks[cur][lm][j*8]);
            short8v a1 = *reinterpret_cast<const short8v*>(&Ks[cur][16 + lm][j*8]);
            s0 = __builtin_amdgcn_mfma_f32_16x16x32_bf16(a0, qf[s], s0, 0, 0, 0);
            s1 = __builtin_amdgcn_mfma_f32_16x16x32_bf16(a1, qf[s], s1, 0, 0, 0);
        }

        // causal mask + online softmax; lane holds kj = ks0 + {4g+r, 16+4g+r} for q = qrow
        float p[8];
        #pragma unroll
        for (int r = 0; r < 4; ++r) {
            int kj0 = ks0 + 4*g + r;
            p[r]     = (kj0      <= qrow) ? s0[r] : -3.0e38f;
            p[r + 4] = (kj0 + 16 <= qrow) ? s1[r] : -3.0e38f;
        }
        float mx = p[0];
        #pragma unroll
        for (int i = 1; i < 8; ++i) mx = fmaxf(mx, p[i]);
        mx = fmaxf(mx, __shfl_xor(mx, 16));
        mx = fmaxf(mx, __shfl_xor(mx, 32));
        float mnew = fmaxf(m_r, mx);
        float corr = __expf(m_r - mnew);       // first tile: expf(-inf)=0
        float psum = 0.f;
        #pragma unroll
        for (int i = 0; i < 8; ++i) { p[i] = __expf(p[i] - mnew); psum += p[i]; }
        psum += __shfl_xor(psum, 16);
        psum += __shfl_xor(psum, 32);
        l_r = l_r * corr + psum;
        m_r = mnew;

        float c4[4];
        #pragma unroll
        for (int r = 0; r < 4; ++r) c4[r] = __shfl(corr, 4*g + r);  // corr for acc-row 4g+r
        #pragma unroll
        for (int dtl = 0; dtl < 16; ++dtl) {
            acc[dtl][0] *= c4[0]; acc[dtl][1] *= c4[1];
            acc[dtl][2] *= c4[2]; acc[dtl][3] *= c4[3];
        }

        // P fragment (lane-local, matches V sigma)
        short8v pf;
        #pragma unroll
        for (int i = 0; i < 8; ++i) pf[i] = f2bf(p[i]);

        // PV over this wave's d-half: B-frag = one contiguous 16B load from sigma-permuted vt
        #pragma unroll
        for (int dtl = 0; dtl < 16; ++dtl) {
            const short* vrow = vp + (size_t)(256*dh + 16*dtl + lm)*TT + ks0 + 8*g;
            short8v v0 = *reinterpret_cast<const short8v*>(vrow);
            acc[dtl] = __builtin_amdgcn_mfma_f32_16x16x32_bf16(pf, v0, acc[dtl], 0, 0, 0);
        }
    }
    #undef STAGE_K

    float inv = 1.f / l_r;
    float i4[4];
    #pragma unroll
    for (int r = 0; r < 4; ++r) i4[r] = __shfl(inv, 4*g + r);
    __hip_bfloat16* cp = ctx + (size_t)b*TT*D;
    #pragma unroll
    for (int dtl = 0; dtl < 16; ++dtl)
        #pragma unroll
        for (int r = 0; r < 4; ++r) {
            int row = qbase + 16*qgp + 4*g + r;
            cp[(size_t)row*D + 256*dh + 16*dtl + lm] = __float2bfloat16(acc[dtl][r] * i4[r]);
        }
}

// ============ Output projection: d_out[t][e] = sum_d ctx[t][d] * Wo[e][d], f32 out ============
__global__ __launch_bounds__(256) void gemm_out(
    const __hip_bfloat16* __restrict__ Ab, const float* __restrict__ W,
    float* __restrict__ Cf)
{
    __shared__ short As[64][72];
    __shared__ short Bs[64][72];
    const int tid = threadIdx.x;
    const int m0 = blockIdx.x * 64, n0 = blockIdx.y * 64;
    const int w = tid >> 6, lane = tid & 63, lm = lane & 15, g = lane >> 4;
    const short* Ap = (const short*)Ab;

    float4v acc[4];
    #pragma unroll
    for (int i = 0; i < 4; ++i) acc[i] = (float4v){0.f,0.f,0.f,0.f};

    for (int k0 = 0; k0 < 512; k0 += 64) {
        __syncthreads();
        #pragma unroll
        for (int u = 0; u < 2; ++u) {          // stage A (bf16 ctx)
            int ch = tid + 256*u;
            int r = ch >> 3, c = (ch & 7) * 8;
            *reinterpret_cast<short8v*>(&As[r][c]) =
                *reinterpret_cast<const short8v*>(Ap + (size_t)(m0 + r)*512 + k0 + c);
        }
        #pragma unroll
        for (int u = 0; u < 4; ++u) {          // stage B (Wo f32 -> bf16)
            int ch = tid + 256*u;
            int r = ch >> 4, c = (ch & 15) * 4;
            float4 wv = *reinterpret_cast<const float4*>(W + (size_t)(n0 + r)*512 + k0 + c);
            short4v sv = { f2bf(wv.x), f2bf(wv.y), f2bf(wv.z), f2bf(wv.w) };
            *reinterpret_cast<short4v*>(&Bs[r][c]) = sv;
        }
        __syncthreads();
        #pragma unroll
        for (int ks = 0; ks < 2; ++ks) {
            short8v a = *reinterpret_cast<const short8v*>(&As[16*w + lm][ks*32 + 8*g]);
            #pragma unroll
            for (int nt = 0; nt < 4; ++nt) {
                short8v bv = *reinterpret_cast<const short8v*>(&Bs[16*nt + lm][ks*32 + 8*g]);
                acc[nt] = __builtin_amdgcn_mfma_f32_16x16x32_bf16(a, bv, acc[nt], 0, 0, 0);
            }
        }
    }
    #pragma unroll
    for (int nt = 0; nt < 4; ++nt)
        #pragma unroll
        for (int r = 0; r < 4; ++r) {
            int row = m0 + 16*w + 4*g + r;
            int col = n0 + 16*nt + lm;
            Cf[(size_t)row*512 + col] = acc[nt][r];
        }
}

extern "C" void kernel_launch(void* const* d_in, const int* in_sizes, int n_in,
                              void* d_out, int out_size, void* d_ws, size_t ws_size,
                              hipStream_t stream) {
    const float* x  = (const float*)d_in[0];
    const float* Wq = (const float*)d_in[1];
    const float* Wk = (const float*)d_in[2];
    const float* Wv = (const float*)d_in[3];
    const float* Wo = (const float*)d_in[4];
    float* out = (float*)d_out;

    const size_t n = (size_t)BB * TT * D;                 // 8.4M elems
    __hip_bfloat16* qb   = (__hip_bfloat16*)d_ws;
    __hip_bfloat16* kb   = qb + n;
    __hip_bfloat16* vb   = kb + n;
    __hip_bfloat16* vt   = vb + n;
    __hip_bfloat16* ctxb = vt + n;                        // total 5n*2B = 80MB

    gemm_qkv<<<dim3(256, 8, 3), 256, 0, stream>>>(x, Wq, Wk, Wv, qb, kb, vb);
    transpose_v<<<dim3(TT / 32, BB), 256, 0, stream>>>(vb, vt);
    attn<<<dim3(128 * BB), 256, 0, stream>>>(qb, kb, vt, ctxb);
    gemm_out<<<dim3(256, 8, 1), 256, 0, stream>>>(ctxb, Wo, out);
}

// Round 6
// 418.940 us; speedup vs baseline: 2.8743x; 1.2672x over previous
//
#include <hip/hip_runtime.h>
#include <hip/hip_bf16.h>
#include <math.h>

#define D 512
#define BB 4
#define TT 4096
#define KT 32

typedef __attribute__((ext_vector_type(8))) short short8v;
typedef __attribute__((ext_vector_type(4))) short short4v;
typedef __attribute__((ext_vector_type(4))) float float4v;

__device__ inline short f2bf(float x) {
    __hip_bfloat16 h = __float2bfloat16(x);
    return *reinterpret_cast<short*>(&h);
}

// ============ QKV projection: C[t][e] = alpha * sum_d x[t][d] * W[e][d], bf16 out ============
__global__ __launch_bounds__(256) void gemm_qkv(
    const float* __restrict__ x,
    const float* __restrict__ Wq, const float* __restrict__ Wk, const float* __restrict__ Wv,
    __hip_bfloat16* __restrict__ q, __hip_bfloat16* __restrict__ k, __hip_bfloat16* __restrict__ v)
{
    const float* W; __hip_bfloat16* C; float alpha;
    if (blockIdx.z == 0)      { W = Wq; C = q; alpha = 0.044194173824159216f; } // fold 1/sqrt(512)
    else if (blockIdx.z == 1) { W = Wk; C = k; alpha = 1.f; }
    else                      { W = Wv; C = v; alpha = 1.f; }

    __shared__ short As[64][72];   // +8 bf16 pad -> conflict-floor b128 reads
    __shared__ short Bs[64][72];
    const int tid = threadIdx.x;
    const int m0 = blockIdx.x * 64, n0 = blockIdx.y * 64;
    const int w = tid >> 6, lane = tid & 63, lm = lane & 15, g = lane >> 4;

    float4v acc[4];
    #pragma unroll
    for (int i = 0; i < 4; ++i) acc[i] = (float4v){0.f,0.f,0.f,0.f};

    for (int k0 = 0; k0 < 512; k0 += 64) {
        __syncthreads();
        #pragma unroll
        for (int u = 0; u < 4; ++u) {          // stage A (x), convert f32->bf16
            int ch = tid + 256*u;
            int r = ch >> 4, c = (ch & 15) * 4;
            float4 xv = *reinterpret_cast<const float4*>(x + (size_t)(m0 + r)*512 + k0 + c);
            short4v sv = { f2bf(xv.x), f2bf(xv.y), f2bf(xv.z), f2bf(xv.w) };
            *reinterpret_cast<short4v*>(&As[r][c]) = sv;
        }
        #pragma unroll
        for (int u = 0; u < 4; ++u) {          // stage B (W rows)
            int ch = tid + 256*u;
            int r = ch >> 4, c = (ch & 15) * 4;
            float4 wv = *reinterpret_cast<const float4*>(W + (size_t)(n0 + r)*512 + k0 + c);
            short4v sv = { f2bf(wv.x), f2bf(wv.y), f2bf(wv.z), f2bf(wv.w) };
            *reinterpret_cast<short4v*>(&Bs[r][c]) = sv;
        }
        __syncthreads();
        #pragma unroll
        for (int ks = 0; ks < 2; ++ks) {
            short8v a = *reinterpret_cast<const short8v*>(&As[16*w + lm][ks*32 + 8*g]);
            #pragma unroll
            for (int nt = 0; nt < 4; ++nt) {
                short8v bv = *reinterpret_cast<const short8v*>(&Bs[16*nt + lm][ks*32 + 8*g]);
                acc[nt] = __builtin_amdgcn_mfma_f32_16x16x32_bf16(a, bv, acc[nt], 0, 0, 0);
            }
        }
    }
    #pragma unroll
    for (int nt = 0; nt < 4; ++nt)
        #pragma unroll
        for (int r = 0; r < 4; ++r) {
            int row = m0 + 16*w + 4*g + r;     // D: row = 4*(lane>>4)+reg, col = lane&15
            int col = n0 + 16*nt + lm;
            C[(size_t)row*512 + col] = __float2bfloat16(acc[nt][r] * alpha);
        }
}

// ============ V transpose with sigma-permuted columns ============
// vt[b][d][32-block of t, order pos(tau)]: pos(tau) = 8*((tau&15)>>2) + (tau&3) + 4*(tau>>4)
// -> position 8g+e within a 32-key block holds key sigma(g,e) = {4g+e, 16+4g+(e-4)}.
__global__ __launch_bounds__(256) void transpose_v(
    const __hip_bfloat16* __restrict__ vin, __hip_bfloat16* __restrict__ vout)
{
    const int tid = threadIdx.x;
    const int b = blockIdx.y;
    const int t = blockIdx.x * 32 + (tid & 31);
    const int tau = t & 31;
    const int tp = (t & ~31) + 8*((tau & 15) >> 2) + (tau & 3) + 4*(tau >> 4);
    const short* src = (const short*)vin + (size_t)(b*TT + t)*D;
    short* dst = (short*)vout + (size_t)b*D*TT;
    #pragma unroll
    for (int u = 0; u < 8; ++u) {
        int cf = (tid >> 5) + 8*u;             // 0..63 (16B chunk within row)
        short8v vv = *reinterpret_cast<const short8v*>(src + cf*8);
        #pragma unroll
        for (int i = 0; i < 8; ++i)
            dst[(size_t)(cf*8 + i)*TT + tp] = vv[i];
    }
}

// ============ Flash attention: 4 waves = 2 q-groups x 2 d-halves; K+V in LDS ============
// Single-buffered K (32x512) and V^T (512x32) tiles, staged per tile via global_load_lds
// with conflict-free XOR swizzles (pre-swizzled global source + matching swizzled read).
// PV in O^T form: acc = mfma(A=V^T, B=P) -> D col = q = lm -> softmax rescale lane-local.
// 2 barriers/tile: [reads of t-1 done] -> stage(t) -> [drain] -> compute(t).
__global__ __launch_bounds__(256, 2) void attn(
    const __hip_bfloat16* __restrict__ qg, const __hip_bfloat16* __restrict__ kg,
    const __hip_bfloat16* __restrict__ vtg, __hip_bfloat16* __restrict__ ctx)
{
    __shared__ short Ks[KT][512];              // 32KB; row r chunk c holds K chunk c^((r&15)<<2)
    __shared__ short Vs[512][32];              // 32KB; row d chunk c holds vt chunk c^((d>>1)&3)

    const int tid = threadIdx.x;
    const int w = tid >> 6, lane = tid & 63, lm = lane & 15, g = lane >> 4;
    const int qgp = w & 1, dh = w >> 1;
    const int idx = blockIdx.x;
    const int b  = idx & 3;                    // batch -> XCD spread
    const int qb = 127 - (idx >> 2);           // descending work order
    const int qbase = qb * 32;
    const int qrow  = qbase + 16*qgp + lm;

    const short* qp = (const short*)qg  + (size_t)b*TT*D;
    const short* kp = (const short*)kg  + (size_t)b*TT*D;
    const short* vp = (const short*)vtg + (size_t)b*D*TT;

    // hoist Q fragments: lane (g,lm) holds Q[qrow][32s+8g .. +8]
    short8v qf[16];
    #pragma unroll
    for (int s = 0; s < 16; ++s)
        qf[s] = *reinterpret_cast<const short8v*>(qp + (size_t)qrow*D + 32*s + 8*g);

    float4v acc[16];                           // O^T: col=q=lm, rows=dims 256*dh+16*dt+4g+r
    #pragma unroll
    for (int i = 0; i < 16; ++i) acc[i] = (float4v){0.f,0.f,0.f,0.f};
    float m_r = -INFINITY, l_r = 0.f;

    const int ntiles = qb + 1;
    const int vswz = (lane & 3) ^ ((lane >> 3) & 3);   // V stage: source chunk for this lane

    for (int t = 0; t < ntiles; ++t) {
        const int ks0 = t * KT;
        __syncthreads();                       // A: all LDS reads of tile t-1 complete

        // stage K: wave w rows 8w..8w+7; lane -> LDS chunk lane, source chunk lane^((r&15)<<2)
        {
            const short* kt_ = kp + (size_t)ks0 * D;
            #pragma unroll
            for (int i_ = 0; i_ < 8; ++i_) {
                int r_ = 8*w + i_;
                int c_ = (lane ^ ((r_ & 15) << 2)) & 63;
                __builtin_amdgcn_global_load_lds(
                    (const __attribute__((address_space(1))) void*)(kt_ + (size_t)r_*D + c_*8),
                    (__attribute__((address_space(3))) void*)(&Ks[r_][0]),
                    16, 0, 0);
            }
        }
        // stage V^T: wave w covers dims 128w..128w+127 (8 instrs x 16 rows)
        {
            #pragma unroll
            for (int i_ = 0; i_ < 8; ++i_) {
                int d0 = 128*w + 16*i_;
                int row_ = d0 + (lane >> 2);
                __builtin_amdgcn_global_load_lds(
                    (const __attribute__((address_space(1))) void*)(vp + (size_t)row_*TT + ks0 + vswz*8),
                    (__attribute__((address_space(3))) void*)(&Vs[d0][0]),
                    16, 0, 0);
            }
        }
        __syncthreads();                       // B: own vmcnt drained per wave -> all DMA landed

        // S^T[kj][q]: 2 subtiles of 16 kj; conflict-free swizzled A-frag reads
        float4v s0 = (float4v){0.f,0.f,0.f,0.f}, s1 = (float4v){0.f,0.f,0.f,0.f};
        #pragma unroll
        for (int s = 0; s < 16; ++s) {
            int j = (4*s + g) ^ (lm << 2);     // 64 lanes -> 64 distinct 16B chunks
            short8v a0 = *reinterpret_cast<const short8v*>(&Ks[lm][j*8]);
            short8v a1 = *reinterpret_cast<const short8v*>(&Ks[16 + lm][j*8]);
            s0 = __builtin_amdgcn_mfma_f32_16x16x32_bf16(a0, qf[s], s0, 0, 0, 0);
            s1 = __builtin_amdgcn_mfma_f32_16x16x32_bf16(a1, qf[s], s1, 0, 0, 0);
        }

        // causal mask + online softmax; lane holds kj = ks0 + sigma(g,e) for q = qrow
        float p[8];
        #pragma unroll
        for (int r = 0; r < 4; ++r) {
            int kj0 = ks0 + 4*g + r;
            p[r]     = (kj0      <= qrow) ? s0[r] : -3.0e38f;
            p[r + 4] = (kj0 + 16 <= qrow) ? s1[r] : -3.0e38f;
        }
        float mx = p[0];
        #pragma unroll
        for (int i = 1; i < 8; ++i) mx = fmaxf(mx, p[i]);
        mx = fmaxf(mx, __shfl_xor(mx, 16));    // reduce across the 4 g-lanes of row lm
        mx = fmaxf(mx, __shfl_xor(mx, 32));
        float mnew = fmaxf(m_r, mx);
        float corr = __expf(m_r - mnew);       // first tile: expf(-inf)=0
        float psum = 0.f;
        #pragma unroll
        for (int i = 0; i < 8; ++i) { p[i] = __expf(p[i] - mnew); psum += p[i]; }
        psum += __shfl_xor(psum, 16);
        psum += __shfl_xor(psum, 32);
        l_r = l_r * corr + psum;
        m_r = mnew;

        // lane-local rescale: every acc element of this lane has col = q = lm
        #pragma unroll
        for (int dt = 0; dt < 16; ++dt) {
            acc[dt][0] *= corr; acc[dt][1] *= corr;
            acc[dt][2] *= corr; acc[dt][3] *= corr;
        }

        // P fragment (lane-local): B-operand elems = P[q=lm][sigma(g,e)]
        short8v pf;
        #pragma unroll
        for (int i = 0; i < 8; ++i) pf[i] = f2bf(p[i]);

        // PV (O^T): A = V^T rows from LDS (2-way floor), B = pf
        #pragma unroll
        for (int dt = 0; dt < 16; ++dt) {
            int rv = 256*dh + 16*dt + lm;
            int cidx = g ^ ((lm >> 1) & 3);
            short8v vf = *reinterpret_cast<const short8v*>(&Vs[rv][cidx*8]);
            acc[dt] = __builtin_amdgcn_mfma_f32_16x16x32_bf16(vf, pf, acc[dt], 0, 0, 0);
        }
    }

    // epilogue: lane-local normalize; lane holds O[q=lm][dims 256dh+16dt+4g..+3]
    float inv = 1.f / l_r;
    __hip_bfloat16* cp = ctx + (size_t)b*TT*D;
    const int orow = qbase + 16*qgp + lm;
    #pragma unroll
    for (int dt = 0; dt < 16; ++dt) {
        short4v o = { f2bf(acc[dt][0]*inv), f2bf(acc[dt][1]*inv),
                      f2bf(acc[dt][2]*inv), f2bf(acc[dt][3]*inv) };
        *reinterpret_cast<short4v*>((short*)cp + (size_t)orow*D + 256*dh + 16*dt + 4*g) = o;
    }
}

// ============ Output projection: d_out[t][e] = sum_d ctx[t][d] * Wo[e][d], f32 out ============
__global__ __launch_bounds__(256) void gemm_out(
    const __hip_bfloat16* __restrict__ Ab, const float* __restrict__ W,
    float* __restrict__ Cf)
{
    __shared__ short As[64][72];
    __shared__ short Bs[64][72];
    const int tid = threadIdx.x;
    const int m0 = blockIdx.x * 64, n0 = blockIdx.y * 64;
    const int w = tid >> 6, lane = tid & 63, lm = lane & 15, g = lane >> 4;
    const short* Ap = (const short*)Ab;

    float4v acc[4];
    #pragma unroll
    for (int i = 0; i < 4; ++i) acc[i] = (float4v){0.f,0.f,0.f,0.f};

    for (int k0 = 0; k0 < 512; k0 += 64) {
        __syncthreads();
        #pragma unroll
        for (int u = 0; u < 2; ++u) {          // stage A (bf16 ctx)
            int ch = tid + 256*u;
            int r = ch >> 3, c = (ch & 7) * 8;
            *reinterpret_cast<short8v*>(&As[r][c]) =
                *reinterpret_cast<const short8v*>(Ap + (size_t)(m0 + r)*512 + k0 + c);
        }
        #pragma unroll
        for (int u = 0; u < 4; ++u) {          // stage B (Wo f32 -> bf16)
            int ch = tid + 256*u;
            int r = ch >> 4, c = (ch & 15) * 4;
            float4 wv = *reinterpret_cast<const float4*>(W + (size_t)(n0 + r)*512 + k0 + c);
            short4v sv = { f2bf(wv.x), f2bf(wv.y), f2bf(wv.z), f2bf(wv.w) };
            *reinterpret_cast<short4v*>(&Bs[r][c]) = sv;
        }
        __syncthreads();
        #pragma unroll
        for (int ks = 0; ks < 2; ++ks) {
            short8v a = *reinterpret_cast<const short8v*>(&As[16*w + lm][ks*32 + 8*g]);
            #pragma unroll
            for (int nt = 0; nt < 4; ++nt) {
                short8v bv = *reinterpret_cast<const short8v*>(&Bs[16*nt + lm][ks*32 + 8*g]);
                acc[nt] = __builtin_amdgcn_mfma_f32_16x16x32_bf16(a, bv, acc[nt], 0, 0, 0);
            }
        }
    }
    #pragma unroll
    for (int nt = 0; nt < 4; ++nt)
        #pragma unroll
        for (int r = 0; r < 4; ++r) {
            int row = m0 + 16*w + 4*g + r;
            int col = n0 + 16*nt + lm;
            Cf[(size_t)row*512 + col] = acc[nt][r];
        }
}

extern "C" void kernel_launch(void* const* d_in, const int* in_sizes, int n_in,
                              void* d_out, int out_size, void* d_ws, size_t ws_size,
                              hipStream_t stream) {
    const float* x  = (const float*)d_in[0];
    const float* Wq = (const float*)d_in[1];
    const float* Wk = (const float*)d_in[2];
    const float* Wv = (const float*)d_in[3];
    const float* Wo = (const float*)d_in[4];
    float* out = (float*)d_out;

    const size_t n = (size_t)BB * TT * D;                 // 8.4M elems
    __hip_bfloat16* qb   = (__hip_bfloat16*)d_ws;
    __hip_bfloat16* kb   = qb + n;
    __hip_bfloat16* vb   = kb + n;
    __hip_bfloat16* vt   = vb + n;
    __hip_bfloat16* ctxb = vt + n;                        // total 5n*2B = 80MB

    gemm_qkv<<<dim3(256, 8, 3), 256, 0, stream>>>(x, Wq, Wk, Wv, qb, kb, vb);
    transpose_v<<<dim3(TT / 32, BB), 256, 0, stream>>>(vb, vt);
    attn<<<dim3(128 * BB), 256, 0, stream>>>(qb, kb, vt, ctxb);
    gemm_out<<<dim3(256, 8, 1), 256, 0, stream>>>(ctxb, Wo, out);
}